// Round 1
// baseline (554.329 us; speedup 1.0000x reference)
//
#include <hip/hip_runtime.h>
#include <math.h>

// DiscriminativeLoss: N=1e6 x D=32 fp32 features, K=64 clusters, scalar out.
// Two passes over features (segment-sum -> means, then hinge distances),
// tiny K^2 epilogue. Memory-bound; no global atomics (all ws writes are
// full overwrites -> no zero-init needed, graph-capture safe).

#define EPS_F 1e-8f
constexpr int D = 32;
constexpr int K = 64;
constexpr int PPAD = 33;                 // +1 pad: bank = (label + off) % 32
constexpr int P1_ELEMS = K * PPAD + K;   // 2112 padded sums + 64 counts = 2176

// ---------------- pass 1: per-block partial segment sums + counts ----------
__global__ __launch_bounds__(256) void pass1_kernel(
    const float* __restrict__ feat, const int* __restrict__ lab,
    float* __restrict__ part1, int N, int nblk)
{
    __shared__ float s_acc[P1_ELEMS];
    for (int i = threadIdx.x; i < P1_ELEMS; i += 256) s_acc[i] = 0.f;
    __syncthreads();
    const int tid  = threadIdx.x;
    const int sub  = tid & 7;    // dim quarter (sub*4 .. sub*4+3)
    const int pofs = tid >> 3;   // point within block batch of 32
    const long long stride = (long long)nblk * 32;
    for (long long p = (long long)blockIdx.x * 32 + pofs; p < N; p += stride) {
        const int l = lab[p];
        const float4 f = *(const float4*)(feat + p * D + sub * 4);
        float* dst = s_acc + l * PPAD + sub * 4;
        atomicAdd(dst + 0, f.x);
        atomicAdd(dst + 1, f.y);
        atomicAdd(dst + 2, f.z);
        atomicAdd(dst + 3, f.w);
        if (sub == 0) atomicAdd(s_acc + K * PPAD + l, 1.0f);
    }
    __syncthreads();
    float* outp = part1 + (long long)blockIdx.x * P1_ELEMS;
    for (int i = tid; i < P1_ELEMS; i += 256) outp[i] = s_acc[i];
}

// ---------------- reduce partials -> means, safe_counts --------------------
__global__ __launch_bounds__(256) void mean_kernel(
    const float* __restrict__ part1, int nblk,
    float* __restrict__ means, float* __restrict__ scnt)
{
    const int e = blockIdx.x * blockDim.x + threadIdx.x;
    if (e >= P1_ELEMS) return;
    if (e >= K * PPAD) {                      // counts column
        float s = 0.f;
        for (int b = 0; b < nblk; b++) s += part1[(long long)b * P1_ELEMS + e];
        scnt[e - K * PPAD] = fmaxf(s, 1.0f);
    } else {
        const int k = e / PPAD, d = e - k * PPAD;
        if (d >= D) return;                   // pad slot
        float s = 0.f, c = 0.f;
        for (int b = 0; b < nblk; b++) {
            const float* pb = part1 + (long long)b * P1_ELEMS;
            s += pb[e];                       // coalesced across threads
            c += pb[K * PPAD + k];            // broadcast within wave, L1-hit
        }
        means[k * D + d] = s / fmaxf(c, 1.0f);
    }
}

// ---------------- pass 2: per-point hinge^2, per-cluster partial sums ------
__global__ __launch_bounds__(256) void pass2_kernel(
    const float* __restrict__ feat, const int* __restrict__ lab,
    const float* __restrict__ means, float* __restrict__ hpart,
    int N, int nblk)
{
    __shared__ float s_h[K];
    for (int i = threadIdx.x; i < K; i += 256) s_h[i] = 0.f;
    __syncthreads();
    const int tid  = threadIdx.x;
    const int sub  = tid & 7;
    const int pofs = tid >> 3;
    const long long stride = (long long)nblk * 32;
    for (long long p = (long long)blockIdx.x * 32 + pofs; p < N; p += stride) {
        const int l = lab[p];
        const float4 f = *(const float4*)(feat + p * D + sub * 4);
        const float4 m = *(const float4*)(means + l * D + sub * 4); // 8KB, L1
        const float dx = f.x - m.x + EPS_F;
        const float dy = f.y - m.y + EPS_F;
        const float dz = f.z - m.z + EPS_F;
        const float dw = f.w - m.w + EPS_F;
        float acc = dx * dx + dy * dy + dz * dz + dw * dw;
        acc += __shfl_xor(acc, 1);            // reduce over 8 lanes (one point)
        acc += __shfl_xor(acc, 2);
        acc += __shfl_xor(acc, 4);
        if (sub == 0) {
            const float dist = sqrtf(acc);
            const float h = fmaxf(dist - 1.5f, 0.f);   // INTRA_MARGIN_USED
            atomicAdd(s_h + l, h * h);
        }
    }
    __syncthreads();
    if (tid < K) hpart[(long long)blockIdx.x * K + tid] = s_h[tid];
}

// ---------------- final: intra + inter + reg -> total ----------------------
__global__ __launch_bounds__(256) void final_kernel(
    const float* __restrict__ hpart, int nblk2,
    const float* __restrict__ means, const float* __restrict__ scnt,
    float* __restrict__ out)
{
    __shared__ float s_m[K * D];      // 8 KB means copy
    __shared__ float s_red[256];
    const int tid = threadIdx.x;
    for (int i = tid; i < K * D; i += 256) s_m[i] = means[i];

    // --- intra: reduce hinge partials (thread = (cluster, quarter)) ---
    {
        const int k = tid & 63, q = tid >> 6;
        float hs = 0.f;
        for (int b = q; b < nblk2; b += 4) hs += hpart[(long long)b * K + k];
        s_red[tid] = hs;
    }
    __syncthreads();
    float v = 0.f;
    if (tid < K) {
        const float hs = s_red[tid] + s_red[tid + 64] + s_red[tid + 128] + s_red[tid + 192];
        v = hs / scnt[tid];           // per-cluster mean hinge^2
    }
    __syncthreads();
    s_red[tid] = v;
    __syncthreads();
    for (int s = 128; s; s >>= 1) { if (tid < s) s_red[tid] += s_red[tid + s]; __syncthreads(); }
    float total = 0.f;
    if (tid == 0) total = s_red[0] * (1.0f / K);
    __syncthreads();

    // --- inter: thread owns column j (means[j] in regs), i rows broadcast ---
    float mj[32];
    const int j = tid & 63;
    {
        const float4* mrow = (const float4*)(means + j * D);
        #pragma unroll
        for (int q = 0; q < 8; q++) {
            const float4 t = mrow[q];
            mj[q * 4 + 0] = t.x; mj[q * 4 + 1] = t.y;
            mj[q * 4 + 2] = t.z; mj[q * 4 + 3] = t.w;
        }
    }
    float isum = 0.f;
    const int igrp = tid >> 6;        // 0..3, 16 i's each
    for (int ii = 0; ii < 16; ii++) {
        const int i = igrp * 16 + ii;
        const float4* srow = (const float4*)(s_m + i * D);  // wave-uniform
        float d2 = 0.f;
        #pragma unroll
        for (int q = 0; q < 8; q++) {
            const float4 mv = srow[q];
            const float a0 = mv.x - mj[q * 4 + 0] + EPS_F;
            const float a1 = mv.y - mj[q * 4 + 1] + EPS_F;
            const float a2 = mv.z - mj[q * 4 + 2] + EPS_F;
            const float a3 = mv.w - mj[q * 4 + 3] + EPS_F;
            d2 += a0 * a0 + a1 * a1 + a2 * a2 + a3 * a3;
        }
        if (i != j) {
            const float pd = sqrtf(d2);
            const float h = fmaxf(1.0f - pd, 0.f);   // 2*INTER_MARGIN_USED - pd
            isum += h * h;
        }
    }
    s_red[tid] = isum;
    __syncthreads();
    for (int s = 128; s; s >>= 1) { if (tid < s) s_red[tid] += s_red[tid + s]; __syncthreads(); }
    if (tid == 0) total += s_red[0] * (1.0f / ((K - 1) * K));
    __syncthreads();

    // --- reg: ||means[j] + EPS|| from registers (threads 0..63 only) ---
    float r = 0.f;
    if (tid < 64) {
        float d2 = 0.f;
        #pragma unroll
        for (int d = 0; d < 32; d++) { const float t = mj[d] + EPS_F; d2 += t * t; }
        r = sqrtf(d2);
    }
    s_red[tid] = r;
    __syncthreads();
    for (int s = 128; s; s >>= 1) { if (tid < s) s_red[tid] += s_red[tid + s]; __syncthreads(); }
    if (tid == 0) out[0] = total + 0.001f * (s_red[0] * (1.0f / K));
}

extern "C" void kernel_launch(void* const* d_in, const int* in_sizes, int n_in,
                              void* d_out, int out_size, void* d_ws, size_t ws_size,
                              hipStream_t stream)
{
    const float* feat = (const float*)d_in[0];
    const int*   lab  = (const int*)d_in[1];
    const int N = in_sizes[1];            // 1e6; D=32, K=64 fixed by reference

    float* ws = (float*)d_ws;
    const long long avail = (long long)(ws_size / 4);

    int nblk1 = 1024, nblk2 = 1024;
    long long need = (long long)K * D + K + (long long)nblk2 * K + (long long)nblk1 * P1_ELEMS;
    if (need > avail) {                   // defensive: shrink to fit workspace
        nblk2 = 128;
        long long rem = avail - K * D - K - (long long)nblk2 * K;
        nblk1 = (int)(rem / P1_ELEMS);
        if (nblk1 > 1024) nblk1 = 1024;
        if (nblk1 < 8) nblk1 = 8;
    }

    float* means = ws;                          // K*D
    float* scnt  = ws + K * D;                  // K
    float* hpart = scnt + K;                    // nblk2*K
    float* part1 = hpart + (long long)nblk2 * K;// nblk1*P1_ELEMS

    pass1_kernel<<<nblk1, 256, 0, stream>>>(feat, lab, part1, N, nblk1);
    mean_kernel<<<(P1_ELEMS + 255) / 256, 256, 0, stream>>>(part1, nblk1, means, scnt);
    pass2_kernel<<<nblk2, 256, 0, stream>>>(feat, lab, means, hpart, N, nblk2);
    final_kernel<<<1, 256, 0, stream>>>(hpart, nblk2, means, scnt, (float*)d_out);
}

// Round 2
// 219.549 us; speedup vs baseline: 2.5249x; 2.5249x over previous
//
#include <hip/hip_runtime.h>
#include <math.h>

// DiscriminativeLoss: N=1e6 x D=32 fp32 features, K=64 clusters, scalar out.
// Two passes over features (segment-sum -> means, then hinge distances),
// parallel tree reductions for all partials (R0's serial reduce was 55% of
// runtime). No global atomics; all ws writes are full overwrites.

#define EPS_F 1e-8f
constexpr int D = 32;
constexpr int K = 64;
constexpr int PPAD = 33;                 // +1 pad: bank = (label + off) % 32
constexpr int P1_ELEMS = K * PPAD + K;   // 2112 padded sums + 64 counts = 2176
constexpr int NCH = 32;                  // reduction chunks for part1

// ---------------- pass 1: per-block partial segment sums + counts ----------
__global__ __launch_bounds__(256) void pass1_kernel(
    const float* __restrict__ feat, const int* __restrict__ lab,
    float* __restrict__ part1, int N, int nblk)
{
    __shared__ float s_acc[P1_ELEMS];
    for (int i = threadIdx.x; i < P1_ELEMS; i += 256) s_acc[i] = 0.f;
    __syncthreads();
    const int tid  = threadIdx.x;
    const int sub  = tid & 7;    // dim quarter (sub*4 .. sub*4+3)
    const int pofs = tid >> 3;   // point within block batch of 32
    const long long stride = (long long)nblk * 32;
    for (long long p = (long long)blockIdx.x * 32 + pofs; p < N; p += stride) {
        const int l = lab[p];
        const float4 f = *(const float4*)(feat + p * D + sub * 4);
        float* dst = s_acc + l * PPAD + sub * 4;
        atomicAdd(dst + 0, f.x);
        atomicAdd(dst + 1, f.y);
        atomicAdd(dst + 2, f.z);
        atomicAdd(dst + 3, f.w);
        if (sub == 0) atomicAdd(s_acc + K * PPAD + l, 1.0f);
    }
    __syncthreads();
    float* outp = part1 + (long long)blockIdx.x * P1_ELEMS;
    for (int i = tid; i < P1_ELEMS; i += 256) outp[i] = s_acc[i];
}

// ---------------- stage A: 1024 partials -> NCH partials (coalesced) -------
__global__ __launch_bounds__(256) void reduce1_kernel(
    const float* __restrict__ part1, float* __restrict__ part2, int chsz)
{
    const int e = blockIdx.x * 256 + threadIdx.x;
    if (e >= P1_ELEMS) return;
    const int y = blockIdx.y;
    const float* src = part1 + (long long)y * chsz * P1_ELEMS;
    float s = 0.f;
    for (int b = 0; b < chsz; b++) s += src[(long long)b * P1_ELEMS + e];
    part2[(long long)y * P1_ELEMS + e] = s;
}

// ---------------- stage B: NCH partials -> means, safe_counts --------------
__global__ __launch_bounds__(256) void mean_kernel(
    const float* __restrict__ part2,
    float* __restrict__ means, float* __restrict__ scnt)
{
    const int e = blockIdx.x * blockDim.x + threadIdx.x;
    if (e >= P1_ELEMS) return;
    if (e >= K * PPAD) {                      // counts column
        float s = 0.f;
        for (int y = 0; y < NCH; y++) s += part2[(long long)y * P1_ELEMS + e];
        scnt[e - K * PPAD] = fmaxf(s, 1.0f);
    } else {
        const int k = e / PPAD, d = e - k * PPAD;
        if (d >= D) return;                   // pad slot
        float s = 0.f, c = 0.f;
        for (int y = 0; y < NCH; y++) {
            const float* pb = part2 + (long long)y * P1_ELEMS;
            s += pb[e];
            c += pb[K * PPAD + k];
        }
        means[k * D + d] = s / fmaxf(c, 1.0f);
    }
}

// ---------------- pass 2: per-point hinge^2, per-cluster partial sums ------
__global__ __launch_bounds__(256) void pass2_kernel(
    const float* __restrict__ feat, const int* __restrict__ lab,
    const float* __restrict__ means, float* __restrict__ hpart,
    int N, int nblk)
{
    __shared__ float s_h[K];
    for (int i = threadIdx.x; i < K; i += 256) s_h[i] = 0.f;
    __syncthreads();
    const int tid  = threadIdx.x;
    const int sub  = tid & 7;
    const int pofs = tid >> 3;
    const long long stride = (long long)nblk * 32;
    for (long long p = (long long)blockIdx.x * 32 + pofs; p < N; p += stride) {
        const int l = lab[p];
        const float4 f = *(const float4*)(feat + p * D + sub * 4);
        const float4 m = *(const float4*)(means + l * D + sub * 4); // 8KB, L1
        const float dx = f.x - m.x + EPS_F;
        const float dy = f.y - m.y + EPS_F;
        const float dz = f.z - m.z + EPS_F;
        const float dw = f.w - m.w + EPS_F;
        float acc = dx * dx + dy * dy + dz * dz + dw * dw;
        acc += __shfl_xor(acc, 1);            // reduce over 8 lanes (one point)
        acc += __shfl_xor(acc, 2);
        acc += __shfl_xor(acc, 4);
        if (sub == 0) {
            const float dist = sqrtf(acc);
            const float h = fmaxf(dist - 1.5f, 0.f);   // INTRA_MARGIN_USED
            atomicAdd(s_h + l, h * h);
        }
    }
    __syncthreads();
    if (tid < K) hpart[(long long)blockIdx.x * K + tid] = s_h[tid];
}

// ---------------- intra: reduce hpart per cluster (parallel) ---------------
__global__ __launch_bounds__(256) void intra_kernel(
    const float* __restrict__ hpart, int nblk2,
    const float* __restrict__ scnt, float* __restrict__ percl)
{
    __shared__ float s_red[256];
    const int k = blockIdx.x;                 // one block per cluster
    const int tid = threadIdx.x;
    float s = 0.f;
    for (int b = tid; b < nblk2; b += 256) s += hpart[(long long)b * K + k];
    s_red[tid] = s;
    __syncthreads();
    for (int st = 128; st; st >>= 1) { if (tid < st) s_red[tid] += s_red[tid + st]; __syncthreads(); }
    if (tid == 0) percl[k] = s_red[0] / scnt[k];
}

// ---------------- final: intra-mean + inter + reg -> total -----------------
__global__ __launch_bounds__(256) void final_kernel(
    const float* __restrict__ percl,
    const float* __restrict__ means, float* __restrict__ out)
{
    __shared__ float s_m[K * D];      // 8 KB means copy
    __shared__ float s_red[256];
    const int tid = threadIdx.x;
    for (int i = tid; i < K * D; i += 256) s_m[i] = means[i];

    float v = (tid < K) ? percl[tid] : 0.f;
    s_red[tid] = v;
    __syncthreads();
    for (int s = 128; s; s >>= 1) { if (tid < s) s_red[tid] += s_red[tid + s]; __syncthreads(); }
    float total = 0.f;
    if (tid == 0) total = s_red[0] * (1.0f / K);
    __syncthreads();

    // --- inter: thread owns column j (means[j] in regs), i rows broadcast ---
    float mj[32];
    const int j = tid & 63;
    {
        const float4* mrow = (const float4*)(means + j * D);
        #pragma unroll
        for (int q = 0; q < 8; q++) {
            const float4 t = mrow[q];
            mj[q * 4 + 0] = t.x; mj[q * 4 + 1] = t.y;
            mj[q * 4 + 2] = t.z; mj[q * 4 + 3] = t.w;
        }
    }
    float isum = 0.f;
    const int igrp = tid >> 6;        // 0..3, 16 i's each
    for (int ii = 0; ii < 16; ii++) {
        const int i = igrp * 16 + ii;
        const float4* srow = (const float4*)(s_m + i * D);  // wave-uniform
        float d2 = 0.f;
        #pragma unroll
        for (int q = 0; q < 8; q++) {
            const float4 mv = srow[q];
            const float a0 = mv.x - mj[q * 4 + 0] + EPS_F;
            const float a1 = mv.y - mj[q * 4 + 1] + EPS_F;
            const float a2 = mv.z - mj[q * 4 + 2] + EPS_F;
            const float a3 = mv.w - mj[q * 4 + 3] + EPS_F;
            d2 += a0 * a0 + a1 * a1 + a2 * a2 + a3 * a3;
        }
        if (i != j) {
            const float pd = sqrtf(d2);
            const float h = fmaxf(1.0f - pd, 0.f);   // 2*INTER_MARGIN_USED - pd
            isum += h * h;
        }
    }
    s_red[tid] = isum;
    __syncthreads();
    for (int s = 128; s; s >>= 1) { if (tid < s) s_red[tid] += s_red[tid + s]; __syncthreads(); }
    if (tid == 0) total += s_red[0] * (1.0f / ((K - 1) * K));
    __syncthreads();

    // --- reg: ||means[j] + EPS|| from registers (threads 0..63 only) ---
    float r = 0.f;
    if (tid < 64) {
        float d2 = 0.f;
        #pragma unroll
        for (int d = 0; d < 32; d++) { const float t = mj[d] + EPS_F; d2 += t * t; }
        r = sqrtf(d2);
    }
    s_red[tid] = r;
    __syncthreads();
    for (int s = 128; s; s >>= 1) { if (tid < s) s_red[tid] += s_red[tid + s]; __syncthreads(); }
    if (tid == 0) out[0] = total + 0.001f * (s_red[0] * (1.0f / K));
}

extern "C" void kernel_launch(void* const* d_in, const int* in_sizes, int n_in,
                              void* d_out, int out_size, void* d_ws, size_t ws_size,
                              hipStream_t stream)
{
    const float* feat = (const float*)d_in[0];
    const int*   lab  = (const int*)d_in[1];
    const int N = in_sizes[1];            // 1e6; D=32, K=64 fixed by reference

    float* ws = (float*)d_ws;
    const long long avail = (long long)(ws_size / 4);

    int nblk1 = 1024, nblk2 = 1024;
    long long fixed = (long long)K * D + K + K + (long long)NCH * P1_ELEMS;
    long long need = fixed + (long long)nblk2 * K + (long long)nblk1 * P1_ELEMS;
    if (need > avail) {                   // defensive: shrink to fit workspace
        nblk2 = 128;
        long long rem = avail - fixed - (long long)nblk2 * K;
        nblk1 = (int)(rem / P1_ELEMS);
        if (nblk1 > 1024) nblk1 = 1024;
        nblk1 -= nblk1 % NCH;             // keep multiple of NCH
        if (nblk1 < NCH) nblk1 = NCH;
    }
    const int chsz = nblk1 / NCH;

    float* means = ws;                          // K*D
    float* scnt  = means + K * D;               // K
    float* percl = scnt + K;                    // K
    float* part2 = percl + K;                   // NCH*P1_ELEMS
    float* hpart = part2 + (long long)NCH * P1_ELEMS;   // nblk2*K
    float* part1 = hpart + (long long)nblk2 * K;        // nblk1*P1_ELEMS

    pass1_kernel<<<nblk1, 256, 0, stream>>>(feat, lab, part1, N, nblk1);
    reduce1_kernel<<<dim3((P1_ELEMS + 255) / 256, NCH), 256, 0, stream>>>(part1, part2, chsz);
    mean_kernel<<<(P1_ELEMS + 255) / 256, 256, 0, stream>>>(part2, means, scnt);
    pass2_kernel<<<nblk2, 256, 0, stream>>>(feat, lab, means, hpart, N, nblk2);
    intra_kernel<<<K, 256, 0, stream>>>(hpart, nblk2, scnt, percl);
    final_kernel<<<1, 256, 0, stream>>>(percl, means, (float*)d_out);
}

// Round 3
// 91.043 us; speedup vs baseline: 6.0886x; 2.4115x over previous
//
#include <hip/hip_runtime.h>
#include <math.h>

// DiscriminativeLoss: N=1e6 x D=32 fp32, K=64, scalar out.
// R2 change: pass1's 3.3e7 LDS-atomic lane-ops (~10 cyc each on the LDS pipe
// = 130us) replaced by block-local counting sort (2 int atomics/point) +
// pure register accumulation with non-atomic writes.

#define EPS_F 1e-8f
constexpr int D = 32;
constexpr int K = 64;
constexpr int NPTS = 1024;               // points per pass1 block
constexpr int P1 = K * D + K;            // 2112: 2048 sums + 64 counts
constexpr int NCH = 32;                  // reduction chunks

// ---------------- pass 1: sort-by-label, register segment sums -------------
__global__ __launch_bounds__(256) void pass1_kernel(
    const float* __restrict__ feat, const int* __restrict__ lab,
    float* __restrict__ part1, int N)
{
    __shared__ int            s_lab[NPTS];
    __shared__ unsigned short s_idx[NPTS];
    __shared__ int            s_hist[K];
    __shared__ int            s_pref[K];
    __shared__ int            s_cur[K];

    const int tid = threadIdx.x;
    const long long base = (long long)blockIdx.x * NPTS;
    int npts = (int)((long long)N - base);
    if (npts > NPTS) npts = NPTS;

    if (tid < K) s_hist[tid] = 0;
    __syncthreads();

    // stage labels (coalesced int4) + histogram (1 int atomic per point)
    const int n4 = npts >> 2;
    for (int i4 = tid; i4 < n4; i4 += 256) {
        const int4 v = ((const int4*)(lab + base))[i4];
        s_lab[i4 * 4 + 0] = v.x; s_lab[i4 * 4 + 1] = v.y;
        s_lab[i4 * 4 + 2] = v.z; s_lab[i4 * 4 + 3] = v.w;
        atomicAdd(&s_hist[v.x], 1); atomicAdd(&s_hist[v.y], 1);
        atomicAdd(&s_hist[v.z], 1); atomicAdd(&s_hist[v.w], 1);
    }
    for (int i = (n4 << 2) + tid; i < npts; i += 256) {  // tail (normally empty)
        const int l = lab[base + i];
        s_lab[i] = l;
        atomicAdd(&s_hist[l], 1);
    }
    __syncthreads();

    // exclusive prefix over 64 bins (wave 0)
    if (tid < 64) {
        const int h = s_hist[tid];
        int v = h;
        for (int off = 1; off < 64; off <<= 1) {
            const int up = __shfl_up(v, off);
            if (tid >= off) v += up;
        }
        s_pref[tid] = v - h;
        s_cur[tid]  = v - h;
    }
    __syncthreads();

    // scatter sorted indices (1 int atomic per point)
    for (int i = tid; i < npts; i += 256) {
        const int l = s_lab[i];
        const int pos = atomicAdd(&s_cur[l], 1);
        s_idx[pos] = (unsigned short)i;
    }
    __syncthreads();

    // register accumulation: thread owns cluster k = tid>>2, dims q*8..q*8+7
    const int k = tid >> 2, q = tid & 3;
    const int start = s_pref[k], len = s_hist[k];
    float4 a0 = {0.f, 0.f, 0.f, 0.f}, a1 = {0.f, 0.f, 0.f, 0.f};
    for (int i = 0; i < len; i++) {
        const int idx = s_idx[start + i];
        const float4* row = (const float4*)(feat + (base + idx) * D + q * 8);
        const float4 x = row[0], y = row[1];
        a0.x += x.x; a0.y += x.y; a0.z += x.z; a0.w += x.w;
        a1.x += y.x; a1.y += y.y; a1.z += y.z; a1.w += y.w;
    }
    float* outp = part1 + (long long)blockIdx.x * P1;
    ((float4*)outp)[tid * 2 + 0] = a0;        // cell k*32 + q*8 == tid*8
    ((float4*)outp)[tid * 2 + 1] = a1;
    if (tid < K) outp[K * D + tid] = (float)s_hist[tid];
}

// ---------------- stage A: nblk1 partials -> NCH partials (coalesced) ------
__global__ __launch_bounds__(256) void reduce1_kernel(
    const float* __restrict__ part1, float* __restrict__ part2,
    int chsz, int nblk1)
{
    const int e = blockIdx.x * 256 + threadIdx.x;
    if (e >= P1) return;
    const int y = blockIdx.y;
    const int b0 = y * chsz;
    int b1 = b0 + chsz; if (b1 > nblk1) b1 = nblk1;
    float s = 0.f;
    for (int b = b0; b < b1; b++) s += part1[(long long)b * P1 + e];
    part2[(long long)y * P1 + e] = s;
}

// ---------------- stage B: NCH partials -> means, safe_counts --------------
__global__ __launch_bounds__(256) void mean_kernel(
    const float* __restrict__ part2,
    float* __restrict__ means, float* __restrict__ scnt)
{
    const int e = blockIdx.x * blockDim.x + threadIdx.x;
    if (e >= P1) return;
    if (e < K * D) {
        float s = 0.f, c = 0.f;
        const int k = e >> 5;
        for (int y = 0; y < NCH; y++) {
            s += part2[(long long)y * P1 + e];
            c += part2[(long long)y * P1 + K * D + k];
        }
        means[e] = s / fmaxf(c, 1.0f);
    } else {
        float s = 0.f;
        for (int y = 0; y < NCH; y++) s += part2[(long long)y * P1 + e];
        scnt[e - K * D] = fmaxf(s, 1.0f);
    }
}

// ---------------- pass 2: per-point hinge^2, per-cluster partial sums ------
__global__ __launch_bounds__(256) void pass2_kernel(
    const float* __restrict__ feat, const int* __restrict__ lab,
    const float* __restrict__ means, float* __restrict__ hpart,
    int N, int nblk)
{
    __shared__ float s_h[K];
    for (int i = threadIdx.x; i < K; i += 256) s_h[i] = 0.f;
    __syncthreads();
    const int tid  = threadIdx.x;
    const int sub  = tid & 7;
    const int pofs = tid >> 3;
    const long long stride = (long long)nblk * 32;
    for (long long p = (long long)blockIdx.x * 32 + pofs; p < N; p += stride) {
        const int l = lab[p];
        const float4 f = *(const float4*)(feat + p * D + sub * 4);
        const float4 m = *(const float4*)(means + l * D + sub * 4); // 8KB, L1
        const float dx = f.x - m.x + EPS_F;
        const float dy = f.y - m.y + EPS_F;
        const float dz = f.z - m.z + EPS_F;
        const float dw = f.w - m.w + EPS_F;
        float acc = dx * dx + dy * dy + dz * dz + dw * dw;
        acc += __shfl_xor(acc, 1);            // reduce over 8 lanes (one point)
        acc += __shfl_xor(acc, 2);
        acc += __shfl_xor(acc, 4);
        if (sub == 0) {
            const float dist = sqrtf(acc);
            const float h = fmaxf(dist - 1.5f, 0.f);   // INTRA_MARGIN_USED
            atomicAdd(s_h + l, h * h);
        }
    }
    __syncthreads();
    if (tid < K) hpart[(long long)blockIdx.x * K + tid] = s_h[tid];
}

// ---------------- intra: reduce hpart per cluster (parallel) ---------------
__global__ __launch_bounds__(256) void intra_kernel(
    const float* __restrict__ hpart, int nblk2,
    const float* __restrict__ scnt, float* __restrict__ percl)
{
    __shared__ float s_red[256];
    const int k = blockIdx.x;                 // one block per cluster
    const int tid = threadIdx.x;
    float s = 0.f;
    for (int b = tid; b < nblk2; b += 256) s += hpart[(long long)b * K + k];
    s_red[tid] = s;
    __syncthreads();
    for (int st = 128; st; st >>= 1) { if (tid < st) s_red[tid] += s_red[tid + st]; __syncthreads(); }
    if (tid == 0) percl[k] = s_red[0] / scnt[k];
}

// ---------------- final: intra-mean + inter + reg -> total -----------------
__global__ __launch_bounds__(256) void final_kernel(
    const float* __restrict__ percl,
    const float* __restrict__ means, float* __restrict__ out)
{
    __shared__ float s_m[K * D];      // 8 KB means copy
    __shared__ float s_red[256];
    const int tid = threadIdx.x;
    for (int i = tid; i < K * D; i += 256) s_m[i] = means[i];

    float v = (tid < K) ? percl[tid] : 0.f;
    s_red[tid] = v;
    __syncthreads();
    for (int s = 128; s; s >>= 1) { if (tid < s) s_red[tid] += s_red[tid + s]; __syncthreads(); }
    float total = 0.f;
    if (tid == 0) total = s_red[0] * (1.0f / K);
    __syncthreads();

    // --- inter: thread owns column j (means[j] in regs), i rows broadcast ---
    float mj[32];
    const int j = tid & 63;
    {
        const float4* mrow = (const float4*)(means + j * D);
        #pragma unroll
        for (int q = 0; q < 8; q++) {
            const float4 t = mrow[q];
            mj[q * 4 + 0] = t.x; mj[q * 4 + 1] = t.y;
            mj[q * 4 + 2] = t.z; mj[q * 4 + 3] = t.w;
        }
    }
    float isum = 0.f;
    const int igrp = tid >> 6;        // 0..3, 16 i's each
    for (int ii = 0; ii < 16; ii++) {
        const int i = igrp * 16 + ii;
        const float4* srow = (const float4*)(s_m + i * D);  // wave-uniform
        float d2 = 0.f;
        #pragma unroll
        for (int q = 0; q < 8; q++) {
            const float4 mv = srow[q];
            const float a0 = mv.x - mj[q * 4 + 0] + EPS_F;
            const float a1 = mv.y - mj[q * 4 + 1] + EPS_F;
            const float a2 = mv.z - mj[q * 4 + 2] + EPS_F;
            const float a3 = mv.w - mj[q * 4 + 3] + EPS_F;
            d2 += a0 * a0 + a1 * a1 + a2 * a2 + a3 * a3;
        }
        if (i != j) {
            const float pd = sqrtf(d2);
            const float h = fmaxf(1.0f - pd, 0.f);   // 2*INTER_MARGIN_USED - pd
            isum += h * h;
        }
    }
    s_red[tid] = isum;
    __syncthreads();
    for (int s = 128; s; s >>= 1) { if (tid < s) s_red[tid] += s_red[tid + s]; __syncthreads(); }
    if (tid == 0) total += s_red[0] * (1.0f / ((K - 1) * K));
    __syncthreads();

    // --- reg: ||means[j] + EPS|| from registers (threads 0..63 only) ---
    float r = 0.f;
    if (tid < 64) {
        float d2 = 0.f;
        #pragma unroll
        for (int d = 0; d < 32; d++) { const float t = mj[d] + EPS_F; d2 += t * t; }
        r = sqrtf(d2);
    }
    s_red[tid] = r;
    __syncthreads();
    for (int s = 128; s; s >>= 1) { if (tid < s) s_red[tid] += s_red[tid + s]; __syncthreads(); }
    if (tid == 0) out[0] = total + 0.001f * (s_red[0] * (1.0f / K));
}

extern "C" void kernel_launch(void* const* d_in, const int* in_sizes, int n_in,
                              void* d_out, int out_size, void* d_ws, size_t ws_size,
                              hipStream_t stream)
{
    const float* feat = (const float*)d_in[0];
    const int*   lab  = (const int*)d_in[1];
    const int N = in_sizes[1];            // 1e6; D=32, K=64 fixed by reference

    float* ws = (float*)d_ws;
    const long long avail = (long long)(ws_size / 4);

    const int nblk1 = (N + NPTS - 1) / NPTS;         // 977
    int nblk2 = 1024;
    const int chsz = (nblk1 + NCH - 1) / NCH;

    long long fixed = (long long)K * D + K + K + (long long)NCH * P1
                      + (long long)nblk1 * P1;
    long long need = fixed + (long long)nblk2 * K;
    if (need > avail) nblk2 = 128;                   // defensive

    float* means = ws;                               // K*D
    float* scnt  = means + K * D;                    // K
    float* percl = scnt + K;                         // K
    float* part2 = percl + K;                        // NCH*P1
    float* hpart = part2 + (long long)NCH * P1;      // nblk2*K
    float* part1 = hpart + (long long)nblk2 * K;     // nblk1*P1

    pass1_kernel<<<nblk1, 256, 0, stream>>>(feat, lab, part1, N);
    reduce1_kernel<<<dim3((P1 + 255) / 256, NCH), 256, 0, stream>>>(part1, part2, chsz, nblk1);
    mean_kernel<<<(P1 + 255) / 256, 256, 0, stream>>>(part2, means, scnt);
    pass2_kernel<<<nblk2, 256, 0, stream>>>(feat, lab, means, hpart, N, nblk2);
    intra_kernel<<<K, 256, 0, stream>>>(hpart, nblk2, scnt, percl);
    final_kernel<<<1, 256, 0, stream>>>(percl, means, (float*)d_out);
}

// Round 4
// 74.790 us; speedup vs baseline: 7.4118x; 1.2173x over previous
//
#include <hip/hip_runtime.h>
#include <math.h>

// DiscriminativeLoss: N=1e6 x D=32 fp32, K=64, scalar out.
// R4: pass2 -> zero-atomic register accumulation of h^2 * inv_count[label]
// (identity: sum_k cluster_sum/cnt = sum_points h^2/cnt_label), 2048 blocks;
// pass1 -> NPTS=512 (7.6 blocks/CU so sort LDS/VALU overlaps gather VMEM
// across blocks), gather unrolled x2. intra_kernel deleted.

#define EPS_F 1e-8f
constexpr int D = 32;
constexpr int K = 64;
constexpr int NPTS = 512;                // points per pass1 block
constexpr int P1 = K * D + K;            // 2112: 2048 sums + 64 counts
constexpr int NCH = 64;                  // reduction chunks
constexpr int NBLK2 = 2048;              // pass2 blocks (8/CU)

// ---------------- pass 1: sort-by-label, register segment sums -------------
__global__ __launch_bounds__(256, 8) void pass1_kernel(
    const float* __restrict__ feat, const int* __restrict__ lab,
    float* __restrict__ part1, int N)
{
    __shared__ int            s_lab[NPTS];
    __shared__ unsigned short s_idx[NPTS];
    __shared__ int            s_hist[K];
    __shared__ int            s_pref[K];
    __shared__ int            s_cur[K];

    const int tid = threadIdx.x;
    const long long base = (long long)blockIdx.x * NPTS;
    int npts = (int)((long long)N - base);
    if (npts > NPTS) npts = NPTS;

    if (tid < K) s_hist[tid] = 0;
    __syncthreads();

    // stage labels (coalesced int4) + histogram (1 int atomic per point)
    const int n4 = npts >> 2;
    for (int i4 = tid; i4 < n4; i4 += 256) {
        const int4 v = ((const int4*)(lab + base))[i4];
        s_lab[i4 * 4 + 0] = v.x; s_lab[i4 * 4 + 1] = v.y;
        s_lab[i4 * 4 + 2] = v.z; s_lab[i4 * 4 + 3] = v.w;
        atomicAdd(&s_hist[v.x], 1); atomicAdd(&s_hist[v.y], 1);
        atomicAdd(&s_hist[v.z], 1); atomicAdd(&s_hist[v.w], 1);
    }
    for (int i = (n4 << 2) + tid; i < npts; i += 256) {  // tail
        const int l = lab[base + i];
        s_lab[i] = l;
        atomicAdd(&s_hist[l], 1);
    }
    __syncthreads();

    // exclusive prefix over 64 bins (wave 0)
    if (tid < 64) {
        const int h = s_hist[tid];
        int v = h;
        for (int off = 1; off < 64; off <<= 1) {
            const int up = __shfl_up(v, off);
            if (tid >= off) v += up;
        }
        s_pref[tid] = v - h;
        s_cur[tid]  = v - h;
    }
    __syncthreads();

    // scatter sorted indices (1 int atomic per point)
    for (int i = tid; i < npts; i += 256) {
        const int l = s_lab[i];
        const int pos = atomicAdd(&s_cur[l], 1);
        s_idx[pos] = (unsigned short)i;
    }
    __syncthreads();

    // register accumulation: thread owns cluster k = tid>>2, dims q*8..q*8+7
    const int k = tid >> 2, q = tid & 3;
    const int start = s_pref[k], len = s_hist[k];
    float4 a0 = {0.f, 0.f, 0.f, 0.f}, a1 = {0.f, 0.f, 0.f, 0.f};
    int i = 0;
    for (; i + 2 <= len; i += 2) {              // unroll x2: 4 loads in flight
        const int i0 = s_idx[start + i];
        const int i1 = s_idx[start + i + 1];
        const float4* r0 = (const float4*)(feat + (base + i0) * D + q * 8);
        const float4* r1 = (const float4*)(feat + (base + i1) * D + q * 8);
        const float4 x0 = r0[0], y0 = r0[1];
        const float4 x1 = r1[0], y1 = r1[1];
        a0.x += x0.x + x1.x; a0.y += x0.y + x1.y;
        a0.z += x0.z + x1.z; a0.w += x0.w + x1.w;
        a1.x += y0.x + y1.x; a1.y += y0.y + y1.y;
        a1.z += y0.z + y1.z; a1.w += y0.w + y1.w;
    }
    if (i < len) {
        const int i0 = s_idx[start + i];
        const float4* r0 = (const float4*)(feat + (base + i0) * D + q * 8);
        const float4 x0 = r0[0], y0 = r0[1];
        a0.x += x0.x; a0.y += x0.y; a0.z += x0.z; a0.w += x0.w;
        a1.x += y0.x; a1.y += y0.y; a1.z += y0.z; a1.w += y0.w;
    }
    float* outp = part1 + (long long)blockIdx.x * P1;
    ((float4*)outp)[tid * 2 + 0] = a0;        // cell k*32 + q*8 == tid*8
    ((float4*)outp)[tid * 2 + 1] = a1;
    if (tid < K) outp[K * D + tid] = (float)s_hist[tid];
}

// ---------------- stage A: nblk1 partials -> NCH partials (coalesced) ------
__global__ __launch_bounds__(256) void reduce1_kernel(
    const float* __restrict__ part1, float* __restrict__ part2,
    int chsz, int nblk1)
{
    const int e = blockIdx.x * 256 + threadIdx.x;
    if (e >= P1) return;
    const int y = blockIdx.y;
    const int b0 = y * chsz;
    int b1 = b0 + chsz; if (b1 > nblk1) b1 = nblk1;
    float s = 0.f;
    for (int b = b0; b < b1; b++) s += part1[(long long)b * P1 + e];
    part2[(long long)y * P1 + e] = s;
}

// ---------------- stage B: NCH partials -> means, inv_counts ---------------
__global__ __launch_bounds__(256) void mean_kernel(
    const float* __restrict__ part2,
    float* __restrict__ means, float* __restrict__ icnt)
{
    const int e = blockIdx.x * blockDim.x + threadIdx.x;
    if (e >= P1) return;
    if (e < K * D) {
        float s = 0.f, c = 0.f;
        const int k = e >> 5;
        for (int y = 0; y < NCH; y++) {
            s += part2[(long long)y * P1 + e];
            c += part2[(long long)y * P1 + K * D + k];
        }
        means[e] = s / fmaxf(c, 1.0f);
    } else {
        float s = 0.f;
        for (int y = 0; y < NCH; y++) s += part2[(long long)y * P1 + e];
        icnt[e - K * D] = 1.0f / fmaxf(s, 1.0f);
    }
}

// ---------------- pass 2: per-point h^2*icnt[l], register accumulation -----
__global__ __launch_bounds__(256, 8) void pass2_kernel(
    const float* __restrict__ feat, const int* __restrict__ lab,
    const float* __restrict__ means, const float* __restrict__ icnt,
    float* __restrict__ hpart, int N)
{
    __shared__ float s_red[256];
    const int tid  = threadIdx.x;
    const int sub  = tid & 7;
    const int pofs = tid >> 3;
    const long long stride = (long long)NBLK2 * 32;
    float racc = 0.f;
    for (long long p = (long long)blockIdx.x * 32 + pofs; p < N; p += stride) {
        const int l = lab[p];
        const float4 f = *(const float4*)(feat + p * D + sub * 4);
        const float4 m = *(const float4*)(means + l * D + sub * 4); // 8KB, L1
        const float dx = f.x - m.x + EPS_F;
        const float dy = f.y - m.y + EPS_F;
        const float dz = f.z - m.z + EPS_F;
        const float dw = f.w - m.w + EPS_F;
        float acc = dx * dx + dy * dy + dz * dz + dw * dw;
        acc += __shfl_xor(acc, 1);            // reduce over 8 lanes (one point)
        acc += __shfl_xor(acc, 2);
        acc += __shfl_xor(acc, 4);
        if (sub == 0) {
            const float dist = sqrtf(acc);
            const float h = fmaxf(dist - 1.5f, 0.f);   // INTRA_MARGIN_USED
            racc += h * h * icnt[l];          // no atomics: register accum
        }
    }
    s_red[tid] = racc;
    __syncthreads();
    for (int st = 128; st; st >>= 1) { if (tid < st) s_red[tid] += s_red[tid + st]; __syncthreads(); }
    if (tid == 0) hpart[blockIdx.x] = s_red[0];
}

// ---------------- final: intra-mean + inter + reg -> total -----------------
__global__ __launch_bounds__(256) void final_kernel(
    const float* __restrict__ hpart,
    const float* __restrict__ means, float* __restrict__ out)
{
    __shared__ float s_m[K * D];      // 8 KB means copy
    __shared__ float s_red[256];
    const int tid = threadIdx.x;
    for (int i = tid; i < K * D; i += 256) s_m[i] = means[i];

    // --- intra: sum 2048 block partials (= sum_k percluster), / K ---
    float hs = 0.f;
    for (int b = tid; b < NBLK2; b += 256) hs += hpart[b];
    s_red[tid] = hs;
    __syncthreads();
    for (int s = 128; s; s >>= 1) { if (tid < s) s_red[tid] += s_red[tid + s]; __syncthreads(); }
    float total = 0.f;
    if (tid == 0) total = s_red[0] * (1.0f / K);
    __syncthreads();

    // --- inter: thread owns column j (means[j] in regs), i rows broadcast ---
    float mj[32];
    const int j = tid & 63;
    {
        const float4* mrow = (const float4*)(means + j * D);
        #pragma unroll
        for (int q = 0; q < 8; q++) {
            const float4 t = mrow[q];
            mj[q * 4 + 0] = t.x; mj[q * 4 + 1] = t.y;
            mj[q * 4 + 2] = t.z; mj[q * 4 + 3] = t.w;
        }
    }
    float isum = 0.f;
    const int igrp = tid >> 6;        // 0..3, 16 i's each
    for (int ii = 0; ii < 16; ii++) {
        const int i = igrp * 16 + ii;
        const float4* srow = (const float4*)(s_m + i * D);  // wave-uniform
        float d2 = 0.f;
        #pragma unroll
        for (int q = 0; q < 8; q++) {
            const float4 mv = srow[q];
            const float a0 = mv.x - mj[q * 4 + 0] + EPS_F;
            const float a1 = mv.y - mj[q * 4 + 1] + EPS_F;
            const float a2 = mv.z - mj[q * 4 + 2] + EPS_F;
            const float a3 = mv.w - mj[q * 4 + 3] + EPS_F;
            d2 += a0 * a0 + a1 * a1 + a2 * a2 + a3 * a3;
        }
        if (i != j) {
            const float pd = sqrtf(d2);
            const float h = fmaxf(1.0f - pd, 0.f);   // 2*INTER_MARGIN_USED - pd
            isum += h * h;
        }
    }
    s_red[tid] = isum;
    __syncthreads();
    for (int s = 128; s; s >>= 1) { if (tid < s) s_red[tid] += s_red[tid + s]; __syncthreads(); }
    if (tid == 0) total += s_red[0] * (1.0f / ((K - 1) * K));
    __syncthreads();

    // --- reg: ||means[j] + EPS|| from registers (threads 0..63 only) ---
    float r = 0.f;
    if (tid < 64) {
        float d2 = 0.f;
        #pragma unroll
        for (int d = 0; d < 32; d++) { const float t = mj[d] + EPS_F; d2 += t * t; }
        r = sqrtf(d2);
    }
    s_red[tid] = r;
    __syncthreads();
    for (int s = 128; s; s >>= 1) { if (tid < s) s_red[tid] += s_red[tid + s]; __syncthreads(); }
    if (tid == 0) out[0] = total + 0.001f * (s_red[0] * (1.0f / K));
}

extern "C" void kernel_launch(void* const* d_in, const int* in_sizes, int n_in,
                              void* d_out, int out_size, void* d_ws, size_t ws_size,
                              hipStream_t stream)
{
    const float* feat = (const float*)d_in[0];
    const int*   lab  = (const int*)d_in[1];
    const int N = in_sizes[1];            // 1e6; D=32, K=64 fixed by reference

    float* ws = (float*)d_ws;

    const int nblk1 = (N + NPTS - 1) / NPTS;         // 1954
    const int chsz  = (nblk1 + NCH - 1) / NCH;       // 31

    float* means = ws;                               // K*D
    float* icnt  = means + K * D;                    // K
    float* part2 = icnt + K;                         // NCH*P1
    float* hpart = part2 + (long long)NCH * P1;      // NBLK2
    float* part1 = hpart + NBLK2;                    // nblk1*P1

    pass1_kernel<<<nblk1, 256, 0, stream>>>(feat, lab, part1, N);
    reduce1_kernel<<<dim3((P1 + 255) / 256, NCH), 256, 0, stream>>>(part1, part2, chsz, nblk1);
    mean_kernel<<<(P1 + 255) / 256, 256, 0, stream>>>(part2, means, icnt);
    pass2_kernel<<<NBLK2, 256, 0, stream>>>(feat, lab, means, icnt, hpart, N);
    final_kernel<<<1, 256, 0, stream>>>(hpart, means, (float*)d_out);
}